// Round 7
// baseline (39.268 us; speedup 1.0000x reference)
//
#include <hip/hip_runtime.h>
#include <hip/hip_bf16.h>
#include <math.h>

#define STU_NUM   100000
#define PROB_NUM  20000
#define KNOW_NUM  128
#define DIM       128
#define BATCH     8192
#define HIDDEN    512

typedef __attribute__((ext_vector_type(4))) float  f32x4;
typedef __attribute__((ext_vector_type(8))) __bf16 bf16x8;

__device__ __forceinline__ float sigmoidf_(float x) { return 1.0f / (1.0f + __expf(-x)); }
__device__ __forceinline__ float tanh_fast(float x) { return 1.0f - 2.0f / (__expf(2.0f * x) + 1.0f); }

// Byte offset of (row, kk) in a [64][64] bf16 LDS tile (8KB), 16B-chunk XOR
// swizzle breaking the row-stride-128B bank alignment (T2). Pattern repeats
// every 8 rows so any row count works.
__device__ __forceinline__ int swz(int row, int kk) {
    return row * 128 + ((((kk >> 3) ^ (row & 7)) << 4) | ((kk & 7) << 1));
}
// Activation buffers: arrays of [64][64] tiles (8KB) along K.
__device__ __forceinline__ bf16x8 rfrag64(const char* buf, int row, int kk) {
    return *reinterpret_cast<const bf16x8*>(buf + (kk >> 6) * 8192 + swz(row, kk & 63));
}
__device__ __forceinline__ void wput64(char* buf, int row, int col, float v) {
    *reinterpret_cast<__bf16*>(buf + (col >> 6) * 8192 + swz(row, col & 63)) = (__bf16)v;
}
__device__ __forceinline__ f32x4 mfma16(bf16x8 a, bf16x8 b, f32x4 c) {
    return __builtin_amdgcn_mfma_f32_16x16x32_bf16(a, b, c, 0, 0, 0);
}

// ---------------------------------------------------------------------------
// Fused kernel: 128 blocks x 64 batch rows, 512 threads (8 waves).
// Halves weight traffic vs 256-block version (weight reuse is cross-block
// only; fewer blocks -> fewer L2 re-fetches). Per-layer weights are loaded
// with FULL breadth up front (all frags in flight) -> one latency exposure
// per layer. LDS 112KB: Xs16|Xk16|st16|h1 64, h2->alias[0,32), h3->alias st.
// ---------------------------------------------------------------------------
__global__ __launch_bounds__(512) void fused_kernel(
    const float* __restrict__ z, const int* __restrict__ sid, const int* __restrict__ eid,
    const float* __restrict__ kp, const float* __restrict__ bstat, const float* __restrict__ bkdiff,
    const float* __restrict__ w_stat, const float* __restrict__ w_kdiff,
    const __bf16* __restrict__ KB, const __bf16* __restrict__ W1T,
    const __bf16* __restrict__ W2T, const __bf16* __restrict__ W3T,
    const float* __restrict__ b1, const float* __restrict__ b2, const float* __restrict__ b3,
    const float* __restrict__ W4, const float* __restrict__ b4,
    float* __restrict__ out) {
    __shared__ char lds[114688];
    char* Xs = lds;              // 16K [64][128]
    char* Xk = lds + 16384;      // 16K
    char* st = lds + 32768;      // 16K
    char* h1 = lds + 49152;      // 64K [64][512]
    char* h2 = lds;              // 32K, aliases Xs+Xk (dead after phase 1)
    char* h3 = lds + 32768;      // 16K, aliases st (dead after layer 1)

    const int t = threadIdx.x, lane = t & 63, wid = t >> 6;   // wid 0..7
    const int l15 = lane & 15, lk = (lane >> 4) * 8;
    const int wm = wid >> 2, wn = wid & 3;                    // phase-1 2row x 4col
    const int rb0 = blockIdx.x * 64;

    // ---- phase 0: gather 128 z-rows; preload KB, W1 slice, kp to regs ----
    #pragma unroll
    for (int q = 0; q < 4; ++q) {
        int idx = q * 512 + t;            // 0..2047
        int row = idx >> 4;               // 0..127
        int c0  = (idx & 15) * 8;
        bool ise = row >= 64;
        int r = row & 63;
        int zrow = ise ? eid[rb0 + r] : sid[rb0 + r];
        const float* w = ise ? w_kdiff : w_stat;
        char* Xb = ise ? Xk : Xs;
        const float4* zp = reinterpret_cast<const float4*>(z + (size_t)zrow * DIM + c0);
        const float4* wp = reinterpret_cast<const float4*>(w + c0);
        float4 za = zp[0], zb = zp[1];
        float4 wa = wp[0], wb = wp[1];
        bf16x8 o;
        o[0] = (__bf16)(za.x * wa.x);  o[1] = (__bf16)(za.y * wa.y);
        o[2] = (__bf16)(za.z * wa.z);  o[3] = (__bf16)(za.w * wa.w);
        o[4] = (__bf16)(zb.x * wb.x);  o[5] = (__bf16)(zb.y * wb.y);
        o[6] = (__bf16)(zb.z * wb.z);  o[7] = (__bf16)(zb.w * wb.w);
        *reinterpret_cast<bf16x8*>(Xb + (c0 >> 6) * 8192 + swz(r, c0 & 63)) = o;
    }
    // KB frags for phase 1: wave covers cols wn*32..+32 (2 colfrags)
    bf16x8 kbf[4][2];
    #pragma unroll
    for (int kt = 0; kt < 4; ++kt)
        #pragma unroll
        for (int c = 0; c < 2; ++c)
            kbf[kt][c] = *reinterpret_cast<const bf16x8*>(
                KB + (size_t)(wn * 32 + c * 16 + l15) * DIM + kt * 32 + lk);
    // W1 slice: wave owns cols wid*64..+64 (4 colfrags), K=128 (4 kt)
    bf16x8 w1f[4][4];
    #pragma unroll
    for (int kt = 0; kt < 4; ++kt)
        #pragma unroll
        for (int c = 0; c < 4; ++c)
            w1f[kt][c] = *reinterpret_cast<const bf16x8*>(
                W1T + (size_t)(wid * 64 + c * 16 + l15) * DIM + kt * 32 + lk);
    // kp for phase-1 epilogue
    float kpv[2][2][4];
    #pragma unroll
    for (int i = 0; i < 2; ++i)
        #pragma unroll
        for (int c = 0; c < 2; ++c)
            #pragma unroll
            for (int r = 0; r < 4; ++r)
                kpv[i][c][r] = kp[(size_t)(rb0 + wm * 32 + i * 16 + (lane >> 4) * 4 + r) * KNOW_NUM
                                  + wn * 32 + c * 16 + l15];
    const float bs = bstat[0], bk = bkdiff[0];
    __syncthreads();

    // ---- phase 1: dual GEMM (Xs,Xk)@KB^T + sigmoid-diff -> st ----
    {
        f32x4 aS[2][2], aK[2][2];
        #pragma unroll
        for (int i = 0; i < 2; ++i)
            #pragma unroll
            for (int c = 0; c < 2; ++c) { aS[i][c] = (f32x4){0,0,0,0}; aK[i][c] = (f32x4){0,0,0,0}; }
        #pragma unroll
        for (int kt = 0; kt < 4; ++kt) {
            const int kk = kt * 32 + lk;
            bf16x8 sA[2], kA[2];
            #pragma unroll
            for (int i = 0; i < 2; ++i) {
                sA[i] = rfrag64(Xs, wm * 32 + i * 16 + l15, kk);
                kA[i] = rfrag64(Xk, wm * 32 + i * 16 + l15, kk);
            }
            #pragma unroll
            for (int i = 0; i < 2; ++i)
                #pragma unroll
                for (int c = 0; c < 2; ++c) {
                    aS[i][c] = mfma16(sA[i], kbf[kt][c], aS[i][c]);
                    aK[i][c] = mfma16(kA[i], kbf[kt][c], aK[i][c]);
                }
        }
        #pragma unroll
        for (int i = 0; i < 2; ++i)
            #pragma unroll
            for (int c = 0; c < 2; ++c)
                #pragma unroll
                for (int r = 0; r < 4; ++r) {
                    int row = wm * 32 + i * 16 + (lane >> 4) * 4 + r;
                    int col = wn * 32 + c * 16 + l15;
                    float v = kpv[i][c][r] *
                              (sigmoidf_(aS[i][c][r] + bs) - sigmoidf_(aK[i][c][r] + bk));
                    wput64(st, row, col, v);
                }
    }
    __syncthreads();

    // ---- layer 1: h1 = tanh(st @ W1^T + b1); weights already in regs ----
    {
        f32x4 acc[4][4];
        #pragma unroll
        for (int rf = 0; rf < 4; ++rf)
            #pragma unroll
            for (int cf = 0; cf < 4; ++cf) acc[rf][cf] = (f32x4){0,0,0,0};
        #pragma unroll
        for (int kt = 0; kt < 4; ++kt) {
            const int kk = kt * 32 + lk;
            bf16x8 a[4];
            #pragma unroll
            for (int rf = 0; rf < 4; ++rf) a[rf] = rfrag64(st, rf * 16 + l15, kk);
            #pragma unroll
            for (int rf = 0; rf < 4; ++rf)
                #pragma unroll
                for (int cf = 0; cf < 4; ++cf)
                    acc[rf][cf] = mfma16(a[rf], w1f[kt][cf], acc[rf][cf]);
        }
        #pragma unroll
        for (int cf = 0; cf < 4; ++cf) {
            int col = wid * 64 + cf * 16 + l15;
            float bv = b1[col];
            #pragma unroll
            for (int rf = 0; rf < 4; ++rf)
                #pragma unroll
                for (int r = 0; r < 4; ++r)
                    wput64(h1, rf * 16 + (lane >> 4) * 4 + r, col, tanh_fast(acc[rf][cf][r] + bv));
        }
    }
    __syncthreads();

    // ---- layer 2: h2 = tanh(h1 @ W2^T + b2); all 32 weight frags in flight ----
    {
        bf16x8 wf[16][2];
        #pragma unroll
        for (int kt = 0; kt < 16; ++kt)
            #pragma unroll
            for (int cf = 0; cf < 2; ++cf)
                wf[kt][cf] = *reinterpret_cast<const bf16x8*>(
                    W2T + (size_t)(wid * 32 + cf * 16 + l15) * HIDDEN + kt * 32 + lk);
        f32x4 acc[4][2];
        #pragma unroll
        for (int rf = 0; rf < 4; ++rf)
            #pragma unroll
            for (int cf = 0; cf < 2; ++cf) acc[rf][cf] = (f32x4){0,0,0,0};
        #pragma unroll
        for (int kt = 0; kt < 16; ++kt) {
            const int kk = kt * 32 + lk;
            bf16x8 a[4];
            #pragma unroll
            for (int rf = 0; rf < 4; ++rf) a[rf] = rfrag64(h1, rf * 16 + l15, kk);
            #pragma unroll
            for (int rf = 0; rf < 4; ++rf)
                #pragma unroll
                for (int cf = 0; cf < 2; ++cf)
                    acc[rf][cf] = mfma16(a[rf], wf[kt][cf], acc[rf][cf]);
        }
        #pragma unroll
        for (int cf = 0; cf < 2; ++cf) {
            int col = wid * 32 + cf * 16 + l15;
            float bv = b2[col];
            #pragma unroll
            for (int rf = 0; rf < 4; ++rf)
                #pragma unroll
                for (int r = 0; r < 4; ++r)
                    wput64(h2, rf * 16 + (lane >> 4) * 4 + r, col, tanh_fast(acc[rf][cf][r] + bv));
        }
    }
    __syncthreads();

    // ---- layer 3: h3 = tanh(h2 @ W3^T + b3); 8 weight frags in flight ----
    {
        bf16x8 wf[8];
        #pragma unroll
        for (int kt = 0; kt < 8; ++kt)
            wf[kt] = *reinterpret_cast<const bf16x8*>(
                W3T + (size_t)(wid * 16 + l15) * (HIDDEN / 2) + kt * 32 + lk);
        f32x4 acc[4];
        #pragma unroll
        for (int rf = 0; rf < 4; ++rf) acc[rf] = (f32x4){0,0,0,0};
        #pragma unroll
        for (int kt = 0; kt < 8; ++kt) {
            const int kk = kt * 32 + lk;
            #pragma unroll
            for (int rf = 0; rf < 4; ++rf)
                acc[rf] = mfma16(rfrag64(h2, rf * 16 + l15, kk), wf[kt], acc[rf]);
        }
        int col = wid * 16 + l15;
        float bv = b3[col];
        #pragma unroll
        for (int rf = 0; rf < 4; ++rf)
            #pragma unroll
            for (int r = 0; r < 4; ++r)
                wput64(h3, rf * 16 + (lane >> 4) * 4 + r, col, tanh_fast(acc[rf][r] + bv));
    }
    __syncthreads();

    // ---- phase 5: out = sigmoid(dot(h3_row, W4) + b4); 2 rows/thread ----
    #pragma unroll
    for (int q = 0; q < 2; ++q) {
        int row  = (t >> 4) + q * 32;    // 0..63
        int part = (t & 15) * 8;
        bf16x8 h = rfrag64(h3, row, part);
        float s = 0.f;
        #pragma unroll
        for (int j = 0; j < 8; ++j) s += (float)h[j] * W4[part + j];
        s += __shfl_xor(s, 1); s += __shfl_xor(s, 2);
        s += __shfl_xor(s, 4); s += __shfl_xor(s, 8);
        if ((t & 15) == 0) out[rb0 + row] = sigmoidf_(s + b4[0]);
    }
}

// ---------------------------------------------------------------------------
// prep: f32 -> bf16 weight reorg, READ-coalesced (writes scattered; stores
// are fire-and-forget). KB [128][128] (= B^T already), W1T/W2T/W3T [N][K].
// ---------------------------------------------------------------------------
__global__ void prep_kernel(const float* __restrict__ z,
                            const float* __restrict__ W1, const float* __restrict__ W2,
                            const float* __restrict__ W3,
                            __bf16* __restrict__ KB, __bf16* __restrict__ W1T,
                            __bf16* __restrict__ W2T, __bf16* __restrict__ W3T) {
    int i = blockIdx.x * 256 + threadIdx.x;
    if (i < 16384) { KB[i] = (__bf16)z[(size_t)(STU_NUM + PROB_NUM) * DIM + i]; return; }
    i -= 16384;
    if (i < 65536) {   // read W1[i] coalesced, write W1T[n][k]
        int k = i >> 9, n = i & 511;
        W1T[(size_t)n * DIM + k] = (__bf16)W1[i]; return;
    }
    i -= 65536;
    if (i < 131072) {  // read W2[i] coalesced
        int k = i >> 8, n = i & 255;
        W2T[(size_t)n * HIDDEN + k] = (__bf16)W2[i]; return;
    }
    i -= 131072;
    if (i < 32768) {   // read W3[i] coalesced
        int k = i >> 7, n = i & 127;
        W3T[(size_t)n * (HIDDEN / 2) + k] = (__bf16)W3[i];
    }
}

extern "C" void kernel_launch(void* const* d_in, const int* in_sizes, int n_in,
                              void* d_out, int out_size, void* d_ws, size_t ws_size,
                              hipStream_t stream) {
    const float* z       = (const float*)d_in[0];
    const int*   sid     = (const int*)d_in[1];
    const int*   eid     = (const int*)d_in[2];
    const float* kp      = (const float*)d_in[3];
    const float* w_stat  = (const float*)d_in[4];
    const float* b_stat  = (const float*)d_in[5];
    const float* w_kdiff = (const float*)d_in[6];
    const float* b_kdiff = (const float*)d_in[7];
    const float* W1      = (const float*)d_in[8];
    const float* b1      = (const float*)d_in[9];
    const float* W2      = (const float*)d_in[10];
    const float* b2      = (const float*)d_in[11];
    const float* W3      = (const float*)d_in[12];
    const float* b3      = (const float*)d_in[13];
    const float* W4      = (const float*)d_in[14];
    const float* b4      = (const float*)d_in[15];
    float* out = (float*)d_out;

    char* ws = (char*)d_ws;
    __bf16* KB  = (__bf16*)(ws + 0);        //  32 KB [128][128]
    __bf16* W1T = (__bf16*)(ws + 32768);    // 128 KB [512][128]
    __bf16* W2T = (__bf16*)(ws + 163840);   // 256 KB [256][512]
    __bf16* W3T = (__bf16*)(ws + 425984);   //  64 KB [128][256]

    hipLaunchKernelGGL(prep_kernel, dim3(960), dim3(256), 0, stream,
                       z, W1, W2, W3, KB, W1T, W2T, W3T);

    hipLaunchKernelGGL(fused_kernel, dim3(BATCH / 64), dim3(512), 0, stream,
                       z, sid, eid, kp, b_stat, b_kdiff, w_stat, w_kdiff,
                       KB, W1T, W2T, W3T, b1, b2, b3, W4, b4, out);
}

// Round 8
// 32.291 us; speedup vs baseline: 1.2161x; 1.2161x over previous
//
#include <hip/hip_runtime.h>
#include <hip/hip_bf16.h>
#include <math.h>

#define STU_NUM   100000
#define PROB_NUM  20000
#define KNOW_NUM  128
#define DIM       128
#define BATCH     8192
#define HIDDEN    512

typedef __attribute__((ext_vector_type(4))) float  f32x4;
typedef __attribute__((ext_vector_type(8))) __bf16 bf16x8;

__device__ __forceinline__ float sigmoidf_(float x) { return 1.0f / (1.0f + __expf(-x)); }
__device__ __forceinline__ float tanh_fast(float x) { return 1.0f - 2.0f / (__expf(2.0f * x) + 1.0f); }

// Byte offset of element (row, kk) inside a [32][64] bf16 LDS tile (4KB),
// 16B-chunk XOR swizzle to break the row-stride-128B bank alignment (T2).
__device__ __forceinline__ int swz(int row, int kk) {
    return row * 128 + ((((kk >> 3) ^ (row & 7)) << 4) | ((kk & 7) << 1));
}
// Activation buffers are arrays of [32][64] tiles along K: tile = kk>>6.
__device__ __forceinline__ bf16x8 rfragK(const char* buf, int row, int kk) {
    return *reinterpret_cast<const bf16x8*>(buf + (kk >> 6) * 4096 + swz(row, kk & 63));
}
__device__ __forceinline__ void wput(char* buf, int row, int col, float v) {
    *reinterpret_cast<__bf16*>(buf + (col >> 6) * 4096 + swz(row, col & 63)) = (__bf16)v;
}
__device__ __forceinline__ f32x4 mfma16(bf16x8 a, bf16x8 b, f32x4 c) {
    return __builtin_amdgcn_mfma_f32_16x16x32_bf16(a, b, c, 0, 0, 0);
}

// ---------------------------------------------------------------------------
// MLP layer, barrier-free k-loop, with BLOCK-STAGGERED k order.
// s is a per-block rotation: kc = (kt + s) & (NKT-1). Decorrelates the weight
// address stream across co-resident blocks so the XCD-L2 serves later
// touchers from cache instead of re-fetching the same line ~10x (R5: 34.6MB
// fetched/rep vs 448KB working set).
// ---------------------------------------------------------------------------
template<int N, int K>
__device__ __forceinline__ void layerG(const __bf16* __restrict__ WT,
                                       const float* __restrict__ bias,
                                       const char* __restrict__ A, char* __restrict__ O,
                                       int wid, int lane, int s) {
    constexpr int NKT = K / 32;
    constexpr int CG = N / 128;
    const int l15 = lane & 15, lk = (lane >> 4) * 8;
    const int nb = wid * (N / 8);
    f32x4 acc[2][CG];
    #pragma unroll
    for (int i = 0; i < 2; ++i)
        #pragma unroll
        for (int c = 0; c < CG; ++c) acc[i][c] = (f32x4){0.f, 0.f, 0.f, 0.f};

    #pragma unroll
    for (int kt = 0; kt < NKT; ++kt) {
        const int kc = (kt + s) & (NKT - 1);   // staggered k order (bijection)
        const int kk = kc * 32 + lk;
        bf16x8 a0 = rfragK(A, l15, kk);
        bf16x8 a1 = rfragK(A, 16 + l15, kk);
        #pragma unroll
        for (int c = 0; c < CG; ++c) {
            bf16x8 b = *reinterpret_cast<const bf16x8*>(WT + (size_t)(nb + c * 16 + l15) * K + kk);
            acc[0][c] = mfma16(a0, b, acc[0][c]);
            acc[1][c] = mfma16(a1, b, acc[1][c]);
        }
    }
    #pragma unroll
    for (int c = 0; c < CG; ++c) {
        const int col = nb + c * 16 + l15;
        const float bv = bias[col];
        #pragma unroll
        for (int i = 0; i < 2; ++i)
            #pragma unroll
            for (int r = 0; r < 4; ++r)
                wput(O, i * 16 + (lane >> 4) * 4 + r, col, tanh_fast(acc[i][c][r] + bv));
    }
}

// ---------------------------------------------------------------------------
// Fused kernel: identical to round 4 (best: 31.8us) except k-stagger.
// 256 blocks x 32 rows, 512 threads (8 waves). LDS 80KB -> 2 blocks/CU.
// ---------------------------------------------------------------------------
__global__ __launch_bounds__(512) void fused_kernel(
    const float* __restrict__ z, const int* __restrict__ sid, const int* __restrict__ eid,
    const float* __restrict__ kp, const float* __restrict__ bstat, const float* __restrict__ bkdiff,
    const float* __restrict__ w_stat, const float* __restrict__ w_kdiff,
    const __bf16* __restrict__ KB, const __bf16* __restrict__ W1T,
    const __bf16* __restrict__ W2T, const __bf16* __restrict__ W3T,
    const float* __restrict__ b1, const float* __restrict__ b2, const float* __restrict__ b3,
    const float* __restrict__ W4, const float* __restrict__ b4,
    float* __restrict__ out) {
    __shared__ char lds[81920];
    char* Xs = lds;
    char* Xk = lds + 8192;
    char* st = lds + 16384;
    char* h1 = lds + 24576;
    char* h2 = lds + 57344;
    char* h3 = lds + 73728;

    const int t = threadIdx.x, lane = t & 63, wid = t >> 6;
    const int l15 = lane & 15, lk = (lane >> 4) * 8;
    const int rb0 = blockIdx.x * 32;
    const int colb = wid * 16 + l15;
    // Per-block stagger seed: blocks on the same XCD (bid = xcd mod 8) get
    // consecutive seeds -> distinct k offsets within each XCD.
    const int sblk = blockIdx.x >> 3;

    // ---- phase 0: gather Xs/Xk into LDS; prefetch KB (staggered) + kp ----
    {
        int gr = t >> 3, row = gr & 31;          // 64 z-rows, 8 threads each
        bool ise = gr >= 32;
        int zrow = ise ? eid[rb0 + row] : sid[rb0 + row];
        const float* w = ise ? w_kdiff : w_stat;
        char* Xb = ise ? Xk : Xs;
        int c0 = (t & 7) * 16;
        const float4* zp = reinterpret_cast<const float4*>(z + (size_t)zrow * DIM + c0);
        const float4* wp = reinterpret_cast<const float4*>(w + c0);
        #pragma unroll
        for (int q = 0; q < 2; ++q) {
            float4 za = zp[2 * q], zb = zp[2 * q + 1];
            float4 wa = wp[2 * q], wb = wp[2 * q + 1];
            bf16x8 o;
            o[0] = (__bf16)(za.x * wa.x);  o[1] = (__bf16)(za.y * wa.y);
            o[2] = (__bf16)(za.z * wa.z);  o[3] = (__bf16)(za.w * wa.w);
            o[4] = (__bf16)(zb.x * wb.x);  o[5] = (__bf16)(zb.y * wb.y);
            o[6] = (__bf16)(zb.z * wb.z);  o[7] = (__bf16)(zb.w * wb.w);
            int c = c0 + q * 8;
            *reinterpret_cast<bf16x8*>(Xb + (c >> 6) * 4096 + swz(row, c & 63)) = o;
        }
    }
    const int sg0 = sblk & 3;
    bf16x8 kbf[4];
    #pragma unroll
    for (int kt = 0; kt < 4; ++kt) {
        const int kc = (kt + sg0) & 3;
        kbf[kt] = *reinterpret_cast<const bf16x8*>(KB + (size_t)colb * DIM + kc * 32 + lk);
    }
    float kpv[2][4];
    #pragma unroll
    for (int i = 0; i < 2; ++i)
        #pragma unroll
        for (int r = 0; r < 4; ++r)
            kpv[i][r] = kp[(size_t)(rb0 + i * 16 + (lane >> 4) * 4 + r) * KNOW_NUM + colb];
    __syncthreads();

    // ---- phase 1: dual GEMM (Xs,Xk)@KB^T + sigmoid-diff -> state ----
    {
        f32x4 aS[2], aK[2];
        #pragma unroll
        for (int i = 0; i < 2; ++i) { aS[i] = (f32x4){0,0,0,0}; aK[i] = (f32x4){0,0,0,0}; }
        #pragma unroll
        for (int kt = 0; kt < 4; ++kt) {
            const int kc = (kt + sg0) & 3;     // matches kbf[kt]'s k-slice
            const int kk = kc * 32 + lk;
            bf16x8 sa0 = rfragK(Xs, l15, kk), sa1 = rfragK(Xs, 16 + l15, kk);
            bf16x8 qa0 = rfragK(Xk, l15, kk), qa1 = rfragK(Xk, 16 + l15, kk);
            aS[0] = mfma16(sa0, kbf[kt], aS[0]);
            aS[1] = mfma16(sa1, kbf[kt], aS[1]);
            aK[0] = mfma16(qa0, kbf[kt], aK[0]);
            aK[1] = mfma16(qa1, kbf[kt], aK[1]);
        }
        const float bs = bstat[0], bk = bkdiff[0];
        #pragma unroll
        for (int i = 0; i < 2; ++i)
            #pragma unroll
            for (int r = 0; r < 4; ++r) {
                float v = kpv[i][r] * (sigmoidf_(aS[i][r] + bs) - sigmoidf_(aK[i][r] + bk));
                wput(st, i * 16 + (lane >> 4) * 4 + r, colb, v);
            }
    }
    __syncthreads();

    // ---- layers 1-3: weights global->reg, block-staggered k order ----
    layerG<HIDDEN,     DIM>       (W1T, b1, st, h1, wid, lane, sblk & 3);
    __syncthreads();
    layerG<HIDDEN / 2, HIDDEN>    (W2T, b2, h1, h2, wid, lane, sblk & 15);
    __syncthreads();
    layerG<HIDDEN / 4, HIDDEN / 2>(W3T, b3, h2, h3, wid, lane, sblk & 7);
    __syncthreads();

    // ---- phase 5: out = sigmoid(dot(h3_row, W4) + b4), 16 lanes/row ----
    {
        int row  = t >> 4;           // 0..31
        int part = (t & 15) * 8;     // 0..120
        bf16x8 h = rfragK(h3, row, part);
        float s = 0.f;
        #pragma unroll
        for (int j = 0; j < 8; ++j) s += (float)h[j] * W4[part + j];
        s += __shfl_xor(s, 1); s += __shfl_xor(s, 2);
        s += __shfl_xor(s, 4); s += __shfl_xor(s, 8);
        if ((t & 15) == 0) out[rb0 + row] = sigmoidf_(s + b4[0]);
    }
}

// ---------------------------------------------------------------------------
// prep: f32 -> bf16 weight reorg, READ-coalesced. Layouts match round 4:
// KB [128][128] (= B^T already), W1T [512][128], W2T [256][512], W3T [128][256].
// ---------------------------------------------------------------------------
__global__ void prep_kernel(const float* __restrict__ z,
                            const float* __restrict__ W1, const float* __restrict__ W2,
                            const float* __restrict__ W3,
                            __bf16* __restrict__ KB, __bf16* __restrict__ W1T,
                            __bf16* __restrict__ W2T, __bf16* __restrict__ W3T) {
    int i = blockIdx.x * 256 + threadIdx.x;
    if (i < 16384) { KB[i] = (__bf16)z[(size_t)(STU_NUM + PROB_NUM) * DIM + i]; return; }
    i -= 16384;
    if (i < 65536) {   // read W1[i] coalesced; W1[k][n] -> W1T[n][k]
        int k = i >> 9, n = i & 511;
        W1T[(size_t)n * DIM + k] = (__bf16)W1[i]; return;
    }
    i -= 65536;
    if (i < 131072) {  // W2[k][n] -> W2T[n][k]
        int k = i >> 8, n = i & 255;
        W2T[(size_t)n * HIDDEN + k] = (__bf16)W2[i]; return;
    }
    i -= 131072;
    if (i < 32768) {   // W3[k][n] -> W3T[n][k]
        int k = i >> 7, n = i & 127;
        W3T[(size_t)n * (HIDDEN / 2) + k] = (__bf16)W3[i];
    }
}

extern "C" void kernel_launch(void* const* d_in, const int* in_sizes, int n_in,
                              void* d_out, int out_size, void* d_ws, size_t ws_size,
                              hipStream_t stream) {
    const float* z       = (const float*)d_in[0];
    const int*   sid     = (const int*)d_in[1];
    const int*   eid     = (const int*)d_in[2];
    const float* kp      = (const float*)d_in[3];
    const float* w_stat  = (const float*)d_in[4];
    const float* b_stat  = (const float*)d_in[5];
    const float* w_kdiff = (const float*)d_in[6];
    const float* b_kdiff = (const float*)d_in[7];
    const float* W1      = (const float*)d_in[8];
    const float* b1      = (const float*)d_in[9];
    const float* W2      = (const float*)d_in[10];
    const float* b2      = (const float*)d_in[11];
    const float* W3      = (const float*)d_in[12];
    const float* b3      = (const float*)d_in[13];
    const float* W4      = (const float*)d_in[14];
    const float* b4      = (const float*)d_in[15];
    float* out = (float*)d_out;

    char* ws = (char*)d_ws;
    __bf16* KB  = (__bf16*)(ws + 0);        //  32 KB [128][128]
    __bf16* W1T = (__bf16*)(ws + 32768);    // 128 KB [512][128]
    __bf16* W2T = (__bf16*)(ws + 163840);   // 256 KB [256][512]
    __bf16* W3T = (__bf16*)(ws + 425984);   //  64 KB [128][256]

    hipLaunchKernelGGL(prep_kernel, dim3(960), dim3(256), 0, stream,
                       z, W1, W2, W3, KB, W1T, W2T, W3T);

    hipLaunchKernelGGL(fused_kernel, dim3(BATCH / 32), dim3(512), 0, stream,
                       z, sid, eid, kp, b_stat, b_kdiff, w_stat, w_kdiff,
                       KB, W1T, W2T, W3T, b1, b2, b3, W4, b4, out);
}